// Round 3
// baseline (3273.057 us; speedup 1.0000x reference)
//
#include <hip/hip_runtime.h>

#define C_ 256
#define H_ 64
#define W_ 64
#define N_ 16
#define HW_ (H_ * W_)

// ---------------------------------------------------------------------------
// Mask kernel: logits[n,h,w] = sum_c x[n,c,h,w] * w_mask[c] + b_mask
// fp64 accumulation of exact fp32 products -> sign(logits) matches the true
// sum; only |logits| < ~1e-6 could disagree with the np fp32 reference.
// ---------------------------------------------------------------------------
__global__ __launch_bounds__(256) void mask_kernel(
    const float* __restrict__ x, const float* __restrict__ wm,
    const float* __restrict__ bm, unsigned char* __restrict__ mask) {
  __shared__ float wms[C_];
  for (int i = threadIdx.x; i < C_; i += 256) wms[i] = wm[i];
  __syncthreads();

  int pix = blockIdx.x * 256 + threadIdx.x;  // N*H*W = 65536 total
  int n = pix >> 12;
  int hw = pix & (HW_ - 1);

  const float* xp = x + (size_t)n * C_ * HW_ + hw;
  double acc = (double)bm[0];
  for (int c = 0; c < C_; c++) {
    acc += (double)xp[(size_t)c * HW_] * (double)wms[c];
  }
  mask[pix] = (acc > 0.0) ? 1 : 0;
}

// ---------------------------------------------------------------------------
// Dilate kernel: 3x3 binary max-pool, SAME padding
// ---------------------------------------------------------------------------
__global__ __launch_bounds__(256) void dilate_kernel(
    const unsigned char* __restrict__ mask, unsigned char* __restrict__ md) {
  int pix = blockIdx.x * 256 + threadIdx.x;
  int n = pix >> 12;
  int hw = pix & (HW_ - 1);
  int h = hw >> 6;
  int w = hw & (W_ - 1);
  int m = 0;
  for (int dy = -1; dy <= 1; dy++) {
    int hh = h + dy;
    if (hh < 0 || hh >= H_) continue;
    for (int dx = -1; dx <= 1; dx++) {
      int ww = w + dx;
      if (ww < 0 || ww >= W_) continue;
      m |= mask[n * HW_ + hh * W_ + ww];
    }
  }
  md[pix] = (unsigned char)m;
}

// ---------------------------------------------------------------------------
// Direct tiled 3x3 conv (fp32), stride 1, pad 1, NCHW / OIHW.
// Block = 256 threads = 16 col-groups (4 cols each) x 16 rows.
// Tile: 16 rows x 64 cols x 16 output channels; full C_in loop inside.
// blockIdx.z is a LOCAL image index within the current batch strip.
// EPI==0: out = gate ? relu(acc) : 0                   (gate = dilated mask)
// EPI==1: out = xres + (gate ? relu(acc) : 0)          (gate = std mask)
// ---------------------------------------------------------------------------
template <int EPI>
__global__ __launch_bounds__(256) void conv3x3_kernel(
    const float* __restrict__ in, const float* __restrict__ wgt,
    const unsigned char* __restrict__ gate, const float* __restrict__ xres,
    float* __restrict__ out) {
  const int tx = threadIdx.x & 15;  // col group: cols 4*tx .. 4*tx+3
  const int ty = threadIdx.x >> 4;  // row within tile
  const int r0 = blockIdx.x * 16;   // first output row of tile
  const int k0 = blockIdx.y * 16;   // first output channel
  const int n = blockIdx.z;         // local image index

  __shared__ float xs[18][68];  // rows r0-1..r0+16, cols -1..64 (+pad)
  __shared__ float wl[16][12];  // 16 out-channels x 9 taps (12 for alignment)

  float acc[16][4];
#pragma unroll
  for (int k = 0; k < 16; k++)
#pragma unroll
    for (int p = 0; p < 4; p++) acc[k][p] = 0.f;

  const size_t base_n = (size_t)n * C_ * HW_;

  for (int c = 0; c < C_; c++) {
    const float* xc = in + base_n + (size_t)c * HW_;
    for (int idx = threadIdx.x; idx < 18 * 66; idx += 256) {
      int i = idx / 66;
      int j = idx - i * 66;
      int hh = r0 - 1 + i;
      int ww = j - 1;
      float v = 0.f;
      if (hh >= 0 && hh < H_ && ww >= 0 && ww < W_) v = xc[hh * W_ + ww];
      xs[i][j] = v;
    }
    if (threadIdx.x < 144) {
      int k = threadIdx.x / 9;
      int j = threadIdx.x - k * 9;
      wl[k][j] = wgt[((size_t)(k0 + k) * C_ + c) * 9 + j];
    }
    __syncthreads();

    // this thread's 3x6 input window: float4 + float2 LDS reads
    float xv[3][6];
#pragma unroll
    for (int dy = 0; dy < 3; dy++) {
      const float4 v4 = *(const float4*)&xs[ty + dy][tx * 4];
      const float2 v2 = *(const float2*)&xs[ty + dy][tx * 4 + 4];
      xv[dy][0] = v4.x; xv[dy][1] = v4.y; xv[dy][2] = v4.z; xv[dy][3] = v4.w;
      xv[dy][4] = v2.x; xv[dy][5] = v2.y;
    }

#pragma unroll
    for (int k = 0; k < 16; k++) {
      const float4 wa = *(const float4*)&wl[k][0];
      const float4 wb = *(const float4*)&wl[k][4];
      const float w8 = wl[k][8];
#pragma unroll
      for (int p = 0; p < 4; p++) {
        acc[k][p] += wa.x * xv[0][p] + wa.y * xv[0][p + 1] + wa.z * xv[0][p + 2] +
                     wa.w * xv[1][p] + wb.x * xv[1][p + 1] + wb.y * xv[1][p + 2] +
                     wb.z * xv[2][p] + wb.w * xv[2][p + 1] + w8 * xv[2][p + 2];
      }
    }
    __syncthreads();
  }

  const int r = r0 + ty;
  const int colbase = tx * 4;
#pragma unroll
  for (int p = 0; p < 4; p++) {
    int hw = r * W_ + colbase + p;
    unsigned char g = gate[n * HW_ + hw];
#pragma unroll
    for (int k = 0; k < 16; k++) {
      float v = g ? fmaxf(acc[k][p], 0.f) : 0.f;
      size_t o = base_n + (size_t)(k0 + k) * HW_ + hw;
      if (EPI == 1) v += xres[o];
      out[o] = v;
    }
  }
}

// ---------------------------------------------------------------------------
extern "C" void kernel_launch(void* const* d_in, const int* in_sizes, int n_in,
                              void* d_out, int out_size, void* d_ws,
                              size_t ws_size, hipStream_t stream) {
  const float* x = (const float*)d_in[0];
  const float* w1 = (const float*)d_in[1];
  const float* w2 = (const float*)d_in[2];
  const float* wm = (const float*)d_in[3];
  const float* bm = (const float*)d_in[4];
  float* out = (float*)d_out;

  // workspace layout: [mask 64KB][md 64KB][h: B images fp32]
  unsigned char* mask = (unsigned char*)d_ws;
  unsigned char* md = mask + N_ * HW_;
  float* h = (float*)((char*)d_ws + 2 * N_ * HW_);

  const size_t img_bytes = (size_t)C_ * HW_ * sizeof(float);  // 4 MiB/image
  size_t avail = (ws_size > (size_t)(2 * N_ * HW_)) ? ws_size - 2 * N_ * HW_ : 0;
  int B = (int)(avail / img_bytes);
  if (B > N_) B = N_;
  if (B < 1) B = 1;

  mask_kernel<<<N_ * HW_ / 256, 256, 0, stream>>>(x, wm, bm, mask);
  dilate_kernel<<<N_ * HW_ / 256, 256, 0, stream>>>(mask, md);

  for (int n0 = 0; n0 < N_; n0 += B) {
    int nb = (N_ - n0 < B) ? (N_ - n0) : B;
    dim3 grid(H_ / 16, C_ / 16, nb);
    const float* xs = x + (size_t)n0 * C_ * HW_;
    float* os = out + (size_t)n0 * C_ * HW_;
    conv3x3_kernel<0><<<grid, 256, 0, stream>>>(xs, w1, md + n0 * HW_, nullptr, h);
    conv3x3_kernel<1><<<grid, 256, 0, stream>>>(h, w2, mask + n0 * HW_, xs, os);
  }
}

// Round 4
// 395.620 us; speedup vs baseline: 8.2732x; 8.2732x over previous
//
#include <hip/hip_runtime.h>
#include <hip/hip_bf16.h>

#define C_ 256
#define H_ 64
#define W_ 64
#define N_ 16
#define HW_ 4096
#define IMG_ (C_ * HW_)        // 1048576 elems (fp32 image)
#define PADROW_ (66 * 256)     // shorts per padded row
#define PADIMG_ (66 * PADROW_) // 1115136 shorts per padded NHWC image
#define WT_ELEMS_ (9 * 256 * 256)

typedef short bf16x8 __attribute__((ext_vector_type(8)));
typedef float f32x4 __attribute__((ext_vector_type(4)));

__device__ __forceinline__ unsigned short f2bf(float f) {
  __hip_bfloat16 h = __float2bfloat16(f);  // RTNE
  return *reinterpret_cast<unsigned short*>(&h);
}

__device__ __forceinline__ void gld_lds16(const void* g, void* l) {
  __builtin_amdgcn_global_load_lds(
      (const __attribute__((address_space(1))) void*)g,
      (__attribute__((address_space(3))) void*)l, 16, 0, 0);
}

// ---------------------------------------------------------------------------
// Mask: logits[n,h,w] = sum_c x[n,c,h,w]*wm[c] + bm ; fp64 acc -> exact sign
// ---------------------------------------------------------------------------
__global__ __launch_bounds__(256) void mask_kernel(
    const float* __restrict__ x, const float* __restrict__ wm,
    const float* __restrict__ bm, unsigned char* __restrict__ mask) {
  __shared__ float wms[C_];
  for (int i = threadIdx.x; i < C_; i += 256) wms[i] = wm[i];
  __syncthreads();
  int pix = blockIdx.x * 256 + threadIdx.x;
  int n = pix >> 12;
  int hw = pix & (HW_ - 1);
  const float* xp = x + (size_t)n * IMG_ + hw;
  double acc = (double)bm[0];
  for (int c = 0; c < C_; c++) acc += (double)xp[(size_t)c * HW_] * (double)wms[c];
  mask[pix] = (acc > 0.0) ? 1 : 0;
}

__global__ __launch_bounds__(256) void dilate_kernel(
    const unsigned char* __restrict__ mask, unsigned char* __restrict__ md) {
  int pix = blockIdx.x * 256 + threadIdx.x;
  int n = pix >> 12;
  int hw = pix & (HW_ - 1);
  int h = hw >> 6, w = hw & 63;
  int m = 0;
  for (int dy = -1; dy <= 1; dy++) {
    int hh = h + dy;
    if (hh < 0 || hh >= H_) continue;
    for (int dx = -1; dx <= 1; dx++) {
      int ww = w + dx;
      if (ww < 0 || ww >= W_) continue;
      m |= mask[n * HW_ + hh * W_ + ww];
    }
  }
  md[pix] = (unsigned char)m;
}

// ---------------------------------------------------------------------------
// Weight transform: Wt[t][k][c] = bf16(w[k][c*9+t])   (t = r*3+s)
// ---------------------------------------------------------------------------
__global__ __launch_bounds__(256) void wt_kernel(
    const float* __restrict__ w1, const float* __restrict__ w2,
    short* __restrict__ Wt1, short* __restrict__ Wt2) {
  const int k = blockIdx.x, c = threadIdx.x;
  const float* src = blockIdx.y ? w2 : w1;
  short* dst = blockIdx.y ? Wt2 : Wt1;
  const float* s = src + ((size_t)k * 256 + c) * 9;
#pragma unroll
  for (int t = 0; t < 9; ++t)
    dst[t * 65536 + k * 256 + c] = (short)f2bf(s[t]);
}

// ---------------------------------------------------------------------------
// x -> zero-padded NHWC bf16: Xp[img][h+1][w+1][c] = bf16(x[img][c][h][w])
// One block per (h, img): LDS-transposed, coalesced both sides.
// ---------------------------------------------------------------------------
__global__ __launch_bounds__(256) void xpad_kernel(
    const float* __restrict__ x, short* __restrict__ Xp) {
  __shared__ unsigned short lds[64 * 260];
  const int h = blockIdx.x, img = blockIdx.y;
  const int tid = threadIdx.x;
  const int wv = tid >> 6, wl = tid & 63;
  const float* xi = x + (size_t)img * IMG_ + h * 64;
#pragma unroll 4
  for (int i = 0; i < 64; ++i) {
    int c = i * 4 + wv;
    lds[wl * 260 + c] = f2bf(xi[(size_t)c * HW_ + wl]);
  }
  __syncthreads();
  short* Xpi = Xp + (size_t)img * PADIMG_ + ((h + 1) * 66 + 1) * 256;
#pragma unroll
  for (int j = 0; j < 16; ++j) {
    int w = j * 4 + wv;
    int c4 = wl * 4;
    uint2 d = *(const uint2*)&lds[w * 260 + c4];
    *(uint2*)&Xpi[(size_t)w * 256 + c4] = d;
  }
}

// ---------------------------------------------------------------------------
// Implicit-GEMM 3x3 conv, bf16 MFMA 16x16x32. Tile: 128 ch x 128 px, BK=32,
// K-loop = 9 taps x 8 substeps. src is padded NHWC (shifts = ptr offsets).
// EPI 0: dstH[padded NHWC] = g ? relu(acc) : 0        (g = dilated mask)
// EPI 1: dstF[NCHW fp32]   = xres + (g ? relu(acc):0) (g = std mask)
// ---------------------------------------------------------------------------
template <int EPI>
__global__ __launch_bounds__(256) void conv_mfma(
    const short* __restrict__ src, const short* __restrict__ Wt,
    const unsigned char* __restrict__ gate, const float* __restrict__ xres,
    short* __restrict__ dstH, float* __restrict__ dstF) {
  __shared__ short As[128 * 32];
  __shared__ short Bs[128 * 32];

  const int tid = threadIdx.x;
  const int lane = tid & 63, wave = tid >> 6;
  const int wm = wave >> 1, wn = wave & 1;
  const int quad = lane >> 4, ln15 = lane & 15;
  const int ch0 = blockIdx.x * 128;
  const int h0 = blockIdx.y * 2;
  const int img = blockIdx.z;

  const int sp = lane >> 2;       // sub-row within 16-row staging chunk
  const int sc = (lane & 3) * 8;  // 16B chunk offset (shorts)

  const int tp0 = wave * 32 + sp;
  const int tp1 = tp0 + 16;
  const short* gB0 = src + (size_t)img * PADIMG_ +
                     ((h0 + (tp0 >> 6)) * 66 + (tp0 & 63)) * 256 + sc;
  const short* gB1 = src + (size_t)img * PADIMG_ +
                     ((h0 + (tp1 >> 6)) * 66 + (tp1 & 63)) * 256 + sc;
  const short* gA0 = Wt + (ch0 + wave * 32 + sp) * 256 + sc;
  const short* gA1 = gA0 + 16 * 256;
  short* lB0 = Bs + (wave * 32) * 32;
  short* lB1 = lB0 + 16 * 32;
  short* lA0 = As + (wave * 32) * 32;
  short* lA1 = lA0 + 16 * 32;

  f32x4 acc[4][4];
#pragma unroll
  for (int i = 0; i < 4; ++i)
#pragma unroll
    for (int j = 0; j < 4; ++j) acc[i][j] = {0.f, 0.f, 0.f, 0.f};

  for (int t = 0; t < 9; ++t) {
    const int toffB = ((t / 3) * 66 + (t % 3)) * 256;  // tap shift (shorts)
    const int toffA = t * 65536;
#pragma unroll
    for (int kk = 0; kk < 8; ++kk) {
      const int ko = kk * 32;
      gld_lds16(gA0 + toffA + ko, lA0);
      gld_lds16(gA1 + toffA + ko, lA1);
      gld_lds16(gB0 + toffB + ko, lB0);
      gld_lds16(gB1 + toffB + ko, lB1);
      __syncthreads();
      bf16x8 a[4], b[4];
#pragma unroll
      for (int i = 0; i < 4; ++i)
        a[i] = *(const bf16x8*)&As[(wm * 64 + i * 16 + ln15) * 32 + quad * 8];
#pragma unroll
      for (int j = 0; j < 4; ++j)
        b[j] = *(const bf16x8*)&Bs[(wn * 64 + j * 16 + ln15) * 32 + quad * 8];
#pragma unroll
      for (int i = 0; i < 4; ++i)
#pragma unroll
        for (int j = 0; j < 4; ++j)
          acc[i][j] = __builtin_amdgcn_mfma_f32_16x16x32_bf16(a[i], b[j],
                                                              acc[i][j], 0, 0, 0);
      __syncthreads();
    }
  }

  // Epilogue. D layout: col(pixel) = lane&15, row(channel) = quad*4 + reg.
  const int chb = ch0 + wm * 64 + quad * 4;
#pragma unroll
  for (int j = 0; j < 4; ++j) {
    const int tp = wn * 64 + j * 16 + ln15;
    const int ph = h0 + (tp >> 6), pw = tp & 63;
    const int pidx = ph * 64 + pw;
    const unsigned char g = gate[img * HW_ + pidx];
#pragma unroll
    for (int i = 0; i < 4; ++i) {
      f32x4 v = acc[i][j];
      const int ch = chb + i * 16;
      float e0 = g ? fmaxf(v[0], 0.f) : 0.f;
      float e1 = g ? fmaxf(v[1], 0.f) : 0.f;
      float e2 = g ? fmaxf(v[2], 0.f) : 0.f;
      float e3 = g ? fmaxf(v[3], 0.f) : 0.f;
      if (EPI == 0) {
        uint2 u;
        u.x = (unsigned int)f2bf(e0) | ((unsigned int)f2bf(e1) << 16);
        u.y = (unsigned int)f2bf(e2) | ((unsigned int)f2bf(e3) << 16);
        short* d = dstH + (size_t)img * PADIMG_ +
                   ((ph + 1) * 66 + (pw + 1)) * 256 + ch;
        *(uint2*)d = u;
      } else {
        size_t o = (size_t)img * IMG_ + (size_t)ch * HW_ + pidx;
        dstF[o] = xres[o] + e0;
        dstF[o + HW_] = xres[o + HW_] + e1;
        dstF[o + 2 * HW_] = xres[o + 2 * HW_] + e2;
        dstF[o + 3 * HW_] = xres[o + 3 * HW_] + e3;
      }
    }
  }
}

// ---------------------------------------------------------------------------
extern "C" void kernel_launch(void* const* d_in, const int* in_sizes, int n_in,
                              void* d_out, int out_size, void* d_ws,
                              size_t ws_size, hipStream_t stream) {
  const float* x = (const float*)d_in[0];
  const float* w1 = (const float*)d_in[1];
  const float* w2 = (const float*)d_in[2];
  const float* wmask = (const float*)d_in[3];
  const float* bmask = (const float*)d_in[4];
  float* out = (float*)d_out;

  char* ws = (char*)d_ws;
  unsigned char* mask = (unsigned char*)ws;                  // 64 KB
  unsigned char* md = (unsigned char*)(ws + 65536);          // 64 KB
  short* Wt1 = (short*)(ws + 131072);                        // 1.125 MiB
  short* Wt2 = Wt1 + WT_ELEMS_;                              // 1.125 MiB
  short* Xp = (short*)(ws + 2490368);

  const size_t fixed = 2490368;
  const size_t per_img = 2 * (size_t)PADIMG_ * 2;  // Xp + Hp bytes per image
  int B = (ws_size > fixed) ? (int)((ws_size - fixed) / per_img) : 0;
  if (B > N_) B = N_;
  if (B < 1) B = 1;
  short* Hp = Xp + (size_t)B * PADIMG_;
  const size_t used = fixed + (size_t)B * per_img;

  hipMemsetAsync(d_ws, 0, used, stream);  // zero halos (ws is re-poisoned)
  wt_kernel<<<dim3(256, 2), 256, 0, stream>>>(w1, w2, Wt1, Wt2);
  mask_kernel<<<256, 256, 0, stream>>>(x, wmask, bmask, mask);
  dilate_kernel<<<256, 256, 0, stream>>>(mask, md);

  for (int n0 = 0; n0 < N_; n0 += B) {
    const int nb = (N_ - n0 < B) ? (N_ - n0) : B;
    xpad_kernel<<<dim3(64, nb), 256, 0, stream>>>(x + (size_t)n0 * IMG_, Xp);
    conv_mfma<0><<<dim3(2, 32, nb), 256, 0, stream>>>(
        Xp, Wt1, md + n0 * HW_, nullptr, Hp, nullptr);
    conv_mfma<1><<<dim3(2, 32, nb), 256, 0, stream>>>(
        Hp, Wt2, mask + n0 * HW_, x + (size_t)n0 * IMG_, nullptr,
        out + (size_t)n0 * IMG_);
  }
}

// Round 5
// 322.746 us; speedup vs baseline: 10.1413x; 1.2258x over previous
//
#include <hip/hip_runtime.h>
#include <hip/hip_bf16.h>

#define C_ 256
#define H_ 64
#define W_ 64
#define N_ 16
#define HW_ 4096
#define IMG_ (C_ * HW_)        // 1048576 elems (fp32 image)
#define PADIMG_ (66 * 66 * 256)  // 1115136 shorts per padded NHWC image
#define WT_ELEMS_ (9 * 256 * 256)

typedef short bf16x8 __attribute__((ext_vector_type(8)));
typedef float f32x4 __attribute__((ext_vector_type(4)));

__device__ __forceinline__ unsigned short f2bf(float f) {
  __hip_bfloat16 h = __float2bfloat16(f);  // RTNE
  return *reinterpret_cast<unsigned short*>(&h);
}

__device__ __forceinline__ void gld_lds16(const void* g, void* l) {
  __builtin_amdgcn_global_load_lds(
      (const __attribute__((address_space(1))) void*)g,
      (__attribute__((address_space(3))) void*)l, 16, 0, 0);
}

// ---------------------------------------------------------------------------
// Mask: logits[n,h,w] = sum_c x[n,c,h,w]*wm[c] + bm ; fp64 acc -> exact sign
// ---------------------------------------------------------------------------
__global__ __launch_bounds__(256) void mask_kernel(
    const float* __restrict__ x, const float* __restrict__ wm,
    const float* __restrict__ bm, unsigned char* __restrict__ mask) {
  __shared__ float wms[C_];
  for (int i = threadIdx.x; i < C_; i += 256) wms[i] = wm[i];
  __syncthreads();
  int pix = blockIdx.x * 256 + threadIdx.x;
  int n = pix >> 12;
  int hw = pix & (HW_ - 1);
  const float* xp = x + (size_t)n * IMG_ + hw;
  double acc = (double)bm[0];
  for (int c = 0; c < C_; c++) acc += (double)xp[(size_t)c * HW_] * (double)wms[c];
  mask[pix] = (acc > 0.0) ? 1 : 0;
}

__global__ __launch_bounds__(256) void dilate_kernel(
    const unsigned char* __restrict__ mask, unsigned char* __restrict__ md) {
  int pix = blockIdx.x * 256 + threadIdx.x;
  int n = pix >> 12;
  int hw = pix & (HW_ - 1);
  int h = hw >> 6, w = hw & 63;
  int m = 0;
  for (int dy = -1; dy <= 1; dy++) {
    int hh = h + dy;
    if (hh < 0 || hh >= H_) continue;
    for (int dx = -1; dx <= 1; dx++) {
      int ww = w + dx;
      if (ww < 0 || ww >= W_) continue;
      m |= mask[n * HW_ + hh * W_ + ww];
    }
  }
  md[pix] = (unsigned char)m;
}

// ---------------------------------------------------------------------------
// Weight transform: Wt[t][k][c] = bf16(w[k][c*9+t])   (t = r*3+s)
// ---------------------------------------------------------------------------
__global__ __launch_bounds__(256) void wt_kernel(
    const float* __restrict__ w1, const float* __restrict__ w2,
    short* __restrict__ Wt1, short* __restrict__ Wt2) {
  const int k = blockIdx.x, c = threadIdx.x;
  const float* src = blockIdx.y ? w2 : w1;
  short* dst = blockIdx.y ? Wt2 : Wt1;
  const float* s = src + ((size_t)k * 256 + c) * 9;
#pragma unroll
  for (int t = 0; t < 9; ++t)
    dst[t * 65536 + k * 256 + c] = (short)f2bf(s[t]);
}

// ---------------------------------------------------------------------------
// Zero the padded halo (rows 0,65; cols 0,65) of Xp and Hp. 512 B per block.
// ---------------------------------------------------------------------------
__global__ __launch_bounds__(128) void halo_zero(short* __restrict__ Xp,
                                                 short* __restrict__ Hp) {
  int p = blockIdx.x;  // 0..259 halo pixel id
  int r, c;
  if (p < 66) { r = 0; c = p; }
  else if (p < 132) { r = 65; c = p - 66; }
  else if (p < 196) { r = p - 131; c = 0; }
  else { r = p - 195; c = 65; }
  short* buf = blockIdx.z ? Hp : Xp;
  unsigned int* d = (unsigned int*)(buf + (size_t)blockIdx.y * PADIMG_ +
                                    (size_t)(r * 66 + c) * 256);
  d[threadIdx.x] = 0u;
}

// ---------------------------------------------------------------------------
// x -> zero-padded NHWC bf16: Xp[img][h+1][w+1][c] = bf16(x[img][c][h][w])
// ---------------------------------------------------------------------------
__global__ __launch_bounds__(256) void xpad_kernel(
    const float* __restrict__ x, short* __restrict__ Xp) {
  __shared__ unsigned short lds[64 * 260];
  const int h = blockIdx.x, img = blockIdx.y;
  const int tid = threadIdx.x;
  const int wv = tid >> 6, wl = tid & 63;
  const float* xi = x + (size_t)img * IMG_ + h * 64;
#pragma unroll 4
  for (int i = 0; i < 64; ++i) {
    int c = i * 4 + wv;
    lds[wl * 260 + c] = f2bf(xi[(size_t)c * HW_ + wl]);
  }
  __syncthreads();
  short* Xpi = Xp + (size_t)img * PADIMG_ + ((h + 1) * 66 + 1) * 256;
#pragma unroll
  for (int j = 0; j < 16; ++j) {
    int w = j * 4 + wv;
    int c4 = wl * 4;
    uint2 d = *(const uint2*)&lds[w * 260 + c4];
    *(uint2*)&Xpi[(size_t)w * 256 + c4] = d;
  }
}

// ---------------------------------------------------------------------------
// Implicit-GEMM 3x3 conv with 9-tap B-reuse from LDS.
// Block: 64 out-ch x 256 px (4 rows x 64 cols). 4 waves; wave w = row h0+w.
// Per 32-ch K-chunk: stage pixel halo block (6 rows x 66 x 32ch, 25.6 KB)
// + all 9 taps' weights (64ch x 32 x 9, 36 KB) once, then 144 MFMA/wave
// between ONE barrier pair. Tap shifts are LDS address offsets.
// EPI 0: dstH[padded NHWC] = g ? relu(acc) : 0        (g = dilated mask)
// EPI 1: dstF[NCHW fp32]   = xres + (g ? relu(acc):0) (g = std mask)
// ---------------------------------------------------------------------------
template <int EPI>
__global__ __launch_bounds__(256) void conv_mfma(
    const short* __restrict__ src, const short* __restrict__ Wt,
    const unsigned char* __restrict__ gate, const float* __restrict__ xres,
    short* __restrict__ dstH, float* __restrict__ dstF) {
  __shared__ short Wl[9 * 64 * 32];  // 36 KB: [tap][out-ch 64][kc 32]
  __shared__ short Bl[400 * 32];     // 25.6 KB: [padded px 396(+4)][kc 32]

  const int tid = threadIdx.x;
  const int lane = tid & 63, wave = tid >> 6;
  const int quad = lane >> 4, ln15 = lane & 15;
  const int ch0 = blockIdx.x * 64;
  const int h0 = blockIdx.y * 4;  // 4 output rows per block
  const int img = blockIdx.z;

  const int lr = lane >> 2;       // row-within-16 for staging
  const int lc = (lane & 3) * 8;  // shorts offset within 32-ch chunk

  // padded rows h0..h0+5 start at padded pixel h0*66
  const short* Xbase = src + (size_t)img * PADIMG_ + (size_t)(h0 * 66) * 256;

  f32x4 acc[4][4];
#pragma unroll
  for (int i = 0; i < 4; ++i)
#pragma unroll
    for (int j = 0; j < 4; ++j) acc[i][j] = {0.f, 0.f, 0.f, 0.f};

  for (int kk = 0; kk < 8; ++kk) {
    const int ko = kk * 32;
    // stage B halo block: 25 wave-insts cover 400 px slots (396 used)
    for (int n = wave; n < 25; n += 4) {
      gld_lds16(Xbase + (size_t)(n * 16 + lr) * 256 + ko + lc, Bl + n * 512);
    }
    // stage A: all 9 taps; wave w covers out-ch rows [w*16, w*16+16)
#pragma unroll
    for (int t = 0; t < 9; ++t) {
      gld_lds16(Wt + t * 65536 + (ch0 + wave * 16 + lr) * 256 + ko + lc,
                Wl + (t * 64 + wave * 16) * 32);
    }
    __syncthreads();

#pragma unroll
    for (int t = 0; t < 9; ++t) {
      const int dy = t / 3, dx = t % 3;
      bf16x8 a[4], b[4];
#pragma unroll
      for (int i = 0; i < 4; ++i)
        a[i] = *(const bf16x8*)&Wl[(t * 64 + i * 16 + ln15) * 32 + quad * 8];
#pragma unroll
      for (int j = 0; j < 4; ++j) {
        const int pl = (wave + dy) * 66 + j * 16 + ln15 + dx;
        b[j] = *(const bf16x8*)&Bl[pl * 32 + quad * 8];
      }
#pragma unroll
      for (int i = 0; i < 4; ++i)
#pragma unroll
        for (int j = 0; j < 4; ++j)
          acc[i][j] = __builtin_amdgcn_mfma_f32_16x16x32_bf16(a[i], b[j],
                                                              acc[i][j], 0, 0, 0);
    }
    __syncthreads();
  }

  // Epilogue. D layout: col(pixel)=ln15, row(channel)=quad*4+reg.
  const int r = h0 + wave;
#pragma unroll
  for (int j = 0; j < 4; ++j) {
    const int col = j * 16 + ln15;
    const int pidx = r * 64 + col;
    const unsigned char g = gate[img * HW_ + pidx];
#pragma unroll
    for (int i = 0; i < 4; ++i) {
      f32x4 v = acc[i][j];
      const int ch = ch0 + i * 16 + quad * 4;
      float e0 = g ? fmaxf(v[0], 0.f) : 0.f;
      float e1 = g ? fmaxf(v[1], 0.f) : 0.f;
      float e2 = g ? fmaxf(v[2], 0.f) : 0.f;
      float e3 = g ? fmaxf(v[3], 0.f) : 0.f;
      if (EPI == 0) {
        uint2 u;
        u.x = (unsigned int)f2bf(e0) | ((unsigned int)f2bf(e1) << 16);
        u.y = (unsigned int)f2bf(e2) | ((unsigned int)f2bf(e3) << 16);
        short* d = dstH + (size_t)img * PADIMG_ +
                   ((size_t)((r + 1) * 66 + (col + 1))) * 256 + ch;
        *(uint2*)d = u;
      } else {
        size_t o = (size_t)img * IMG_ + (size_t)ch * HW_ + pidx;
        dstF[o] = xres[o] + e0;
        dstF[o + HW_] = xres[o + HW_] + e1;
        dstF[o + 2 * HW_] = xres[o + 2 * HW_] + e2;
        dstF[o + 3 * HW_] = xres[o + 3 * HW_] + e3;
      }
    }
  }
}

// ---------------------------------------------------------------------------
extern "C" void kernel_launch(void* const* d_in, const int* in_sizes, int n_in,
                              void* d_out, int out_size, void* d_ws,
                              size_t ws_size, hipStream_t stream) {
  const float* x = (const float*)d_in[0];
  const float* w1 = (const float*)d_in[1];
  const float* w2 = (const float*)d_in[2];
  const float* wmask = (const float*)d_in[3];
  const float* bmask = (const float*)d_in[4];
  float* out = (float*)d_out;

  char* ws = (char*)d_ws;
  unsigned char* mask = (unsigned char*)ws;          // 64 KB
  unsigned char* md = (unsigned char*)(ws + 65536);  // 64 KB
  short* Wt1 = (short*)(ws + 131072);                // 1.125 MiB
  short* Wt2 = Wt1 + WT_ELEMS_;                      // 1.125 MiB
  short* Xp = (short*)(ws + 2490368);

  const size_t fixed = 2490368;
  const size_t tailpad = 16384;  // B-stage overshoot pad past last image
  const size_t per_img = 2 * (size_t)PADIMG_ * 2;  // Xp + Hp bytes per image
  int B = (ws_size > fixed + tailpad)
              ? (int)((ws_size - fixed - tailpad) / per_img) : 0;
  if (B > N_) B = N_;
  if (B < 1) B = 1;
  short* Hp = Xp + (size_t)B * PADIMG_;

  wt_kernel<<<dim3(256, 2), 256, 0, stream>>>(w1, w2, Wt1, Wt2);
  mask_kernel<<<256, 256, 0, stream>>>(x, wmask, bmask, mask);
  dilate_kernel<<<256, 256, 0, stream>>>(mask, md);
  halo_zero<<<dim3(260, B, 2), 128, 0, stream>>>(Xp, Hp);

  for (int n0 = 0; n0 < N_; n0 += B) {
    const int nb = (N_ - n0 < B) ? (N_ - n0) : B;
    xpad_kernel<<<dim3(64, nb), 256, 0, stream>>>(x + (size_t)n0 * IMG_, Xp);
    conv_mfma<0><<<dim3(4, 16, nb), 256, 0, stream>>>(
        Xp, Wt1, md + n0 * HW_, nullptr, Hp, nullptr);
    conv_mfma<1><<<dim3(4, 16, nb), 256, 0, stream>>>(
        Hp, Wt2, mask + n0 * HW_, x + (size_t)n0 * IMG_, nullptr,
        out + (size_t)n0 * IMG_);
  }
}